// Round 8
// baseline (351.148 us; speedup 1.0000x reference)
//
#include <hip/hip_runtime.h>
#include <stdint.h>

#define TOKENS 8192
#define INF    4096
#define OUTF   4096
#define NTQ    32   // K-tiles of 128 fp8 elements

typedef __bf16 bf16x8 __attribute__((ext_vector_type(8)));
typedef float  f32x4  __attribute__((ext_vector_type(4)));
typedef int    i32x4  __attribute__((ext_vector_type(4)));
typedef int    i32x8  __attribute__((ext_vector_type(8)));
typedef unsigned short ushort_t;
typedef unsigned char  u8;

#if defined(__has_builtin)
#  if __has_builtin(__builtin_amdgcn_mfma_scale_f32_16x16x128_f8f6f4) && \
      __has_builtin(__builtin_amdgcn_cvt_pk_fp8_f32)
#    define HAS_MX 1
#  else
#    define HAS_MX 0
#  endif
#else
#  define HAS_MX 0
#endif

// ---------- async global->LDS, 16B/lane (dest = wave base + lane*16) ---------
__device__ __forceinline__ void gload_lds16(const void* g, void* l) {
  auto gp = reinterpret_cast<__attribute__((address_space(1))) unsigned int*>(
      reinterpret_cast<uintptr_t>(g));
  auto lp = reinterpret_cast<__attribute__((address_space(3))) unsigned int*>(
      reinterpret_cast<uintptr_t>(l));
  __builtin_amdgcn_global_load_lds(gp, lp, 16, 0, 0);
}

// ---------- st_16x32 swizzle on byte offsets within a 16 KiB half-slot -------
__device__ __forceinline__ int swz(int b) { return b ^ (((b >> 9) & 1) << 5); }

__device__ __forceinline__ f32x4 mfma(bf16x8 a, bf16x8 b, f32x4 c) {
  return __builtin_amdgcn_mfma_f32_16x16x32_bf16(a, b, c, 0, 0, 0);
}

template <int N>
__device__ __forceinline__ void vmwait() {
  if constexpr (N == 4)      asm volatile("s_waitcnt vmcnt(4)" ::: "memory");
  else if constexpr (N == 0) asm volatile("s_waitcnt vmcnt(0)" ::: "memory");
}

// R3-proven phase sync (sched_barrier is load-bearing: R6 ablation -13%)
#define PHASE_SYNC()                                            \
  __builtin_amdgcn_s_barrier();                                 \
  asm volatile("s_waitcnt lgkmcnt(0)" ::: "memory");            \
  __builtin_amdgcn_sched_barrier(0);                            \
  __builtin_amdgcn_s_setprio(1)

#define PHASE_END() __builtin_amdgcn_s_setprio(0)
#define BAR() __builtin_amdgcn_s_barrier()

// ---------- fp32 -> bf16 (RNE) (fallback path) ----------
__device__ __forceinline__ unsigned short f2bf(float f) {
  union { float f; unsigned int u; } v;
  v.f = f;
  unsigned int r = v.u + 0x7fffu + ((v.u >> 16) & 1u);
  return (unsigned short)(r >> 16);
}

__global__ void l2b_conv_x(const float* __restrict__ x,
                           unsigned short* __restrict__ xb, int n4) {
  int idx = blockIdx.x * blockDim.x + threadIdx.x;
  int stride = gridDim.x * blockDim.x;
  for (int i = idx; i < n4; i += stride) {
    float4 v = reinterpret_cast<const float4*>(x)[i];
    ushort4 o;
    o.x = f2bf(v.x); o.y = f2bf(v.y); o.z = f2bf(v.z); o.w = f2bf(v.w);
    reinterpret_cast<ushort4*>(xb)[i] = o;
  }
}

__global__ void l2b_conv_w(const int* __restrict__ w,
                           unsigned short* __restrict__ wb, int n4) {
  int idx = blockIdx.x * blockDim.x + threadIdx.x;
  int stride = gridDim.x * blockDim.x;
  for (int i = idx; i < n4; i += stride) {
    int4 v = reinterpret_cast<const int4*>(w)[i];
    ushort4 o;
    o.x = f2bf((float)v.x); o.y = f2bf((float)v.y);
    o.z = f2bf((float)v.z); o.w = f2bf((float)v.w);
    reinterpret_cast<ushort4*>(wb)[i] = o;
  }
}

#if HAS_MX
// ================== fp8 conversions ==================
__global__ void l2b_conv_x_q(const float* __restrict__ x,
                             u8* __restrict__ xq, int n8) {
  int idx = blockIdx.x * blockDim.x + threadIdx.x;
  int stride = gridDim.x * blockDim.x;
  for (int i = idx; i < n8; i += stride) {
    float4 v0 = reinterpret_cast<const float4*>(x)[2 * i];
    float4 v1 = reinterpret_cast<const float4*>(x)[2 * i + 1];
    int u0 = __builtin_amdgcn_cvt_pk_fp8_f32(v0.x, v0.y, 0, false);
    u0 = __builtin_amdgcn_cvt_pk_fp8_f32(v0.z, v0.w, u0, true);
    int u1 = __builtin_amdgcn_cvt_pk_fp8_f32(v1.x, v1.y, 0, false);
    u1 = __builtin_amdgcn_cvt_pk_fp8_f32(v1.z, v1.w, u1, true);
    uint2 o; o.x = (unsigned)u0; o.y = (unsigned)u1;
    reinterpret_cast<uint2*>(xq)[i] = o;
  }
}

// weights {-2,-1,0,1} -> e4m3 exact: LUT byte (idx = w+2): C0 B8 00 38
__device__ __forceinline__ unsigned w2q(int w) {
  return (0x3800B8C0u >> (((unsigned)(w + 2)) * 8)) & 0xFFu;
}

__global__ void l2b_conv_w_q(const int* __restrict__ w,
                             u8* __restrict__ wq, int n8) {
  int idx = blockIdx.x * blockDim.x + threadIdx.x;
  int stride = gridDim.x * blockDim.x;
  for (int i = idx; i < n8; i += stride) {
    int4 a = reinterpret_cast<const int4*>(w)[2 * i];
    int4 b = reinterpret_cast<const int4*>(w)[2 * i + 1];
    uint2 o;
    o.x = w2q(a.x) | (w2q(a.y) << 8) | (w2q(a.z) << 16) | (w2q(a.w) << 24);
    o.y = w2q(b.x) | (w2q(b.y) << 8) | (w2q(b.z) << 16) | (w2q(b.w) << 24);
    reinterpret_cast<uint2*>(wq)[i] = o;
  }
}

// ================== MX-fp8 GEMM pieces ==================
union F8 { i32x4 p[2]; i32x8 v; };

__device__ __forceinline__ i32x4 ldsRdQ(const u8* slot, int row, int colb) {
  int off = (row << 7) | colb;
  off ^= ((off >> 9) & 1) << 5;
  return *reinterpret_cast<const i32x4*>(slot + off);
}

__device__ __forceinline__ void stage_halfQ(const u8* __restrict__ src,
                                            u8* slot, int wid, int ge0, int ge1) {
  gload_lds16(src + ge0, slot + wid * 1024);
  gload_lds16(src + ge1, slot + 8192 + wid * 1024);
}

__device__ __forceinline__ f32x4 mfmaq(i32x8 a, i32x8 b, f32x4 c) {
  // cbsz=0 (A=fp8 e4m3), blgp=0 (B=fp8), scales = e8m0 127 = 1.0, opsel byte 0
  return __builtin_amdgcn_mfma_scale_f32_16x16x128_f8f6f4(
      a, b, c, 0, 0, 0, (int)0x7F7F7F7Fu, 0, (int)0x7F7F7F7Fu);
}

// -------- one K-tile (128 fp8): 4 phases, 8 mfma_scale each (R3 mirror) -----
// reads: ph1 (A0,B0)->acc[0..3][0..1]; ph2 (A0,B1)->acc[0..3][2..3];
//        ph3 (A1,B1)->acc[4..7][2..3]; ph4 (A1,B0)->acc[4..7][0..1]
// stages: ph1 A1(t+1)->oA1; ph2 B0(t+1)->oB0; ph3 A0(t+2)->rA0; ph4 B1(t+2)->rB1
// vmcnt(4) at tile end (R3-proven ledger: oldest 8 of 12 = all of tile t+1).
template <int VMB, bool STG1, bool STG2>
__device__ __forceinline__ void ktileQ(
    const u8* __restrict__ A, const u8* __restrict__ B,
    int rowBlk, int colBlk, int t,
    u8* rA0, u8* rA1, u8* rB0, u8* rB1,
    u8* oA1, u8* oB0,
    f32x4 (&acc)[8][4], int ar, int br, int fk, int wid, int ge0, int ge1) {
  F8 a[4], b[2];
  // ---- phase 1 (12 ds_reads -> early lgkm(8)) ----
#pragma unroll
  for (int m = 0; m < 4; ++m) {
    a[m].p[0] = ldsRdQ(rA0, ar + m * 16, fk * 32);
    a[m].p[1] = ldsRdQ(rA0, ar + m * 16, fk * 32 + 16);
  }
#pragma unroll
  for (int n = 0; n < 2; ++n) {
    b[n].p[0] = ldsRdQ(rB0, br + n * 16, fk * 32);
    b[n].p[1] = ldsRdQ(rB0, br + n * 16, fk * 32 + 16);
  }
  if (STG1)
    stage_halfQ(A + (size_t)(rowBlk + 128) * INF + (t + 1) * 128, oA1, wid, ge0, ge1);
  asm volatile("s_waitcnt lgkmcnt(8)" ::: "memory");
  PHASE_SYNC();
#pragma unroll
  for (int m = 0; m < 4; ++m)
#pragma unroll
    for (int n = 0; n < 2; ++n)
      acc[m][n] = mfmaq(a[m].v, b[n].v, acc[m][n]);
  PHASE_END();
  BAR();
  // ---- phase 2 ----
#pragma unroll
  for (int n = 0; n < 2; ++n) {
    b[n].p[0] = ldsRdQ(rB1, br + n * 16, fk * 32);
    b[n].p[1] = ldsRdQ(rB1, br + n * 16, fk * 32 + 16);
  }
  if (STG1)
    stage_halfQ(B + (size_t)colBlk * INF + (t + 1) * 128, oB0, wid, ge0, ge1);
  PHASE_SYNC();
#pragma unroll
  for (int m = 0; m < 4; ++m)
#pragma unroll
    for (int n = 0; n < 2; ++n)
      acc[m][2 + n] = mfmaq(a[m].v, b[n].v, acc[m][2 + n]);
  PHASE_END();
  BAR();
  // ---- phase 3 (b1 reused from regs) ----
#pragma unroll
  for (int m = 0; m < 4; ++m) {
    a[m].p[0] = ldsRdQ(rA1, ar + m * 16, fk * 32);
    a[m].p[1] = ldsRdQ(rA1, ar + m * 16, fk * 32 + 16);
  }
  if (STG2)
    stage_halfQ(A + (size_t)rowBlk * INF + (t + 2) * 128, rA0, wid, ge0, ge1);
  PHASE_SYNC();
#pragma unroll
  for (int m = 0; m < 4; ++m)
#pragma unroll
    for (int n = 0; n < 2; ++n)
      acc[4 + m][2 + n] = mfmaq(a[m].v, b[n].v, acc[4 + m][2 + n]);
  PHASE_END();
  BAR();
  // ---- phase 4 (re-read B0) ----
#pragma unroll
  for (int n = 0; n < 2; ++n) {
    b[n].p[0] = ldsRdQ(rB0, br + n * 16, fk * 32);
    b[n].p[1] = ldsRdQ(rB0, br + n * 16, fk * 32 + 16);
  }
  if (STG2)
    stage_halfQ(B + (size_t)(colBlk + 128) * INF + (t + 2) * 128, rB1, wid, ge0, ge1);
  PHASE_SYNC();
#pragma unroll
  for (int m = 0; m < 4; ++m)
#pragma unroll
    for (int n = 0; n < 2; ++n)
      acc[4 + m][n] = mfmaq(a[m].v, b[n].v, acc[4 + m][n]);
  PHASE_END();
  if (VMB >= 0) vmwait<VMB >= 0 ? VMB : 0>();
  BAR();
}

// ---------- 256x256 MX-fp8 GEMM, BK=128, 128 KiB LDS (R3 structure) ----------
__global__ __launch_bounds__(512, 2) void l2b_gemm_mx(
    const u8* __restrict__ A, const u8* __restrict__ B,
    const float* __restrict__ scale, const float* __restrict__ bias,
    float* __restrict__ C) {
  extern __shared__ u8 smemq[];  // 128 KiB = 8 half-slots of 16 KiB
  u8* sA00 = smemq;              u8* sA01 = smemq + 16384;
  u8* sA10 = smemq + 32768;      u8* sA11 = smemq + 49152;
  u8* sB00 = smemq + 65536;      u8* sB01 = smemq + 81920;
  u8* sB10 = smemq + 98304;      u8* sB11 = smemq + 114688;

  const int tid  = threadIdx.x;
  const int lane = tid & 63;
  const int wid  = tid >> 6;              // 0..7
  const int wm = wid >> 2, wn = wid & 3;  // 2x4 wave grid
  const int fr = lane & 15, fk = lane >> 4;
  const int ar = wm * 64 + fr;            // a-frag row within half
  const int br = wn * 32 + fr;            // b-frag row within half

  // XCD-aware swizzle (nwg=512, divisible by 8)
  const int bid = (int)blockIdx.x;
  const int idx = (bid & 7) * 64 + (bid >> 3);
  const int bm = idx >> 4, bn = idx & 15;
  const int rowBlk = bm * 256, colBlk = bn * 256;

  // inverse-swizzled per-lane global BYTE offsets for the 2 staging rounds
  const int ob0 = wid * 1024 + lane * 16;
  const int ob1 = 8192 + ob0;
  const int p0 = swz(ob0), p1 = swz(ob1);
  const int ge0 = (p0 >> 7) * INF + (p0 & 127);
  const int ge1 = (p1 >> 7) * INF + (p1 & 127);

  // ---- prologue: A0(0),B1(0),A1(0),B0(0),A0(1),B1(1); vmcnt(4)=tile0 landed
  stage_halfQ(A + (size_t)rowBlk * INF,               sA00, wid, ge0, ge1);
  stage_halfQ(B + (size_t)(colBlk + 128) * INF,       sB01, wid, ge0, ge1);
  stage_halfQ(A + (size_t)(rowBlk + 128) * INF,       sA01, wid, ge0, ge1);
  stage_halfQ(B + (size_t)colBlk * INF,               sB00, wid, ge0, ge1);
  stage_halfQ(A + (size_t)rowBlk * INF + 128,         sA10, wid, ge0, ge1);
  stage_halfQ(B + (size_t)(colBlk + 128) * INF + 128, sB11, wid, ge0, ge1);
  asm volatile("s_waitcnt vmcnt(4)" ::: "memory");
  BAR();

  f32x4 acc[8][4] = {};

#pragma unroll 1
  for (int i = 0; i < (NTQ - 2) / 2; ++i) {            // tiles 0..29
    const int t = 2 * i;
    ktileQ<4, true, true>(A, B, rowBlk, colBlk, t,
        sA00, sA01, sB00, sB01, sA11, sB10,
        acc, ar, br, fk, wid, ge0, ge1);
    ktileQ<4, true, true>(A, B, rowBlk, colBlk, t + 1,
        sA10, sA11, sB10, sB11, sA01, sB00,
        acc, ar, br, fk, wid, ge0, ge1);
  }
  // tile 30 (parity 0): stage only t+1=31; drain vmcnt to 0 at boundary
  ktileQ<0, true, false>(A, B, rowBlk, colBlk, NTQ - 2,
      sA00, sA01, sB00, sB01, sA11, sB10,
      acc, ar, br, fk, wid, ge0, ge1);
  // tile 31 (parity 1): compute only
  ktileQ<-1, false, false>(A, B, rowBlk, colBlk, NTQ - 1,
      sA10, sA11, sB10, sB11, sA01, sB00,
      acc, ar, br, fk, wid, ge0, ge1);

  // ---- epilogue: y = acc*scale + bias; C/D: col=lane&15, row=(lane>>4)*4+j
  const float s = scale[0];
#pragma unroll
  for (int ni = 0; ni < 4; ++ni) {
    const int nh = ni >> 1, n = ni & 1;
    const int col = colBlk + nh * 128 + wn * 32 + n * 16 + fr;
    const float bv = bias[col];
#pragma unroll
    for (int mi = 0; mi < 8; ++mi) {
      const int mh = mi >> 2, m = mi & 3;
      const int row = rowBlk + mh * 128 + wm * 64 + m * 16 + fk * 4;
#pragma unroll
      for (int j = 0; j < 4; ++j)
        C[(size_t)(row + j) * OUTF + col] = acc[mi][ni][j] * s + bv;
    }
  }
}
#endif  // HAS_MX

// ---------------- fallback: R1 128x128 m97-structure bf16 GEMM --------------
__global__ __launch_bounds__(256) void l2b_gemm(
    const ushort_t* __restrict__ A, const ushort_t* __restrict__ B,
    const float* __restrict__ scale, const float* __restrict__ bias,
    float* __restrict__ C) {
  constexpr int K = INF;
  constexpr int N = OUTF;
  __shared__ __align__(16) ushort_t ldsA[128 * 32];
  __shared__ __align__(16) ushort_t ldsB[128 * 32];
  const int tid = threadIdx.x;
  const int lane = tid & 63;
  const int wid = tid >> 6;
  const int wm = wid >> 1, wn = wid & 1;
  const int bm = blockIdx.x >> 5, bn = blockIdx.x & 31;
  const int row0 = bm * 128, col0 = bn * 128;
  const int lr = lane >> 4, lc = lane & 15;
  f32x4 acc[4][4] = {};
  for (int k0 = 0; k0 < K; k0 += 32) {
#pragma unroll
    for (int i = 0; i < 2; ++i) {
      const int idx = i * 256 + tid;
      const int r = idx >> 2;
      const int c = (idx & 3) * 8;
      ushort_t* lbaseA = ldsA + i * 2048 + wid * 512;
      ushort_t* lbaseB = ldsB + i * 2048 + wid * 512;
      gload_lds16(A + (size_t)(row0 + r) * K + (k0 + c), lbaseA);
      gload_lds16(B + (size_t)(col0 + r) * K + (k0 + c), lbaseB);
    }
    __syncthreads();
    bf16x8 af[4], bfr[4];
#pragma unroll
    for (int m = 0; m < 4; ++m)
      af[m] = *reinterpret_cast<const bf16x8*>(
          &ldsA[(wm * 64 + m * 16 + lc) * 32 + lr * 8]);
#pragma unroll
    for (int n = 0; n < 4; ++n)
      bfr[n] = *reinterpret_cast<const bf16x8*>(
          &ldsB[(wn * 64 + n * 16 + lc) * 32 + lr * 8]);
#pragma unroll
    for (int m = 0; m < 4; ++m)
#pragma unroll
      for (int n = 0; n < 4; ++n)
        acc[m][n] = mfma(af[m], bfr[n], acc[m][n]);
    __syncthreads();
  }
  const float s = scale[0];
#pragma unroll
  for (int n = 0; n < 4; ++n) {
    const int col = col0 + wn * 64 + n * 16 + lc;
    const float bv = bias[col];
#pragma unroll
    for (int m = 0; m < 4; ++m) {
      const int row = row0 + wm * 64 + m * 16 + lr * 4;
#pragma unroll
      for (int i = 0; i < 4; ++i)
        C[(size_t)(row + i) * N + col] = acc[m][n][i] * s + bv;
    }
  }
}

__global__ void l2b_naive(const float* __restrict__ x, const int* __restrict__ w,
                          const float* __restrict__ scale,
                          const float* __restrict__ bias,
                          float* __restrict__ out) {
  const int o = blockIdx.x * blockDim.x + threadIdx.x;
  if (o >= TOKENS * OUTF) return;
  const int t = o / OUTF;
  const int n = o - t * OUTF;
  const float* xr = x + (size_t)t * INF;
  const int* wr = w + (size_t)n * INF;
  float acc = 0.f;
  for (int k = 0; k < INF; ++k) acc += xr[k] * (float)wr[k];
  out[o] = acc * scale[0] + bias[n];
}

extern "C" void kernel_launch(void* const* d_in, const int* in_sizes, int n_in,
                              void* d_out, int out_size, void* d_ws, size_t ws_size,
                              hipStream_t stream) {
  const float* x     = (const float*)d_in[0];
  const int*   wq    = (const int*)d_in[1];
  const float* scale = (const float*)d_in[2];
  const float* bias  = (const float*)d_in[3];
  float* out = (float*)d_out;

#if HAS_MX
  const size_t xq_bytes = (size_t)TOKENS * INF;   // 32 MiB fp8
  const size_t wq_bytes = (size_t)OUTF * INF;     // 16 MiB fp8
  if (ws_size >= xq_bytes + wq_bytes) {
    u8* xq = (u8*)d_ws;
    u8* wq8 = xq + xq_bytes;
    hipError_t e = hipFuncSetAttribute(
        reinterpret_cast<const void*>(l2b_gemm_mx),
        hipFuncAttributeMaxDynamicSharedMemorySize, 131072);
    if (e == hipSuccess) {
      l2b_conv_x_q<<<2048, 256, 0, stream>>>(x, xq, TOKENS * INF / 8);
      l2b_conv_w_q<<<2048, 256, 0, stream>>>(wq, wq8, OUTF * INF / 8);
      l2b_gemm_mx<<<dim3((TOKENS / 256) * (OUTF / 256)), 512, 131072, stream>>>(
          xq, wq8, scale, bias, out);
      return;
    }
  }
#endif

  const size_t xbytes = (size_t)TOKENS * INF * 2;
  const size_t wbytes = (size_t)OUTF * INF * 2;
  if (ws_size >= xbytes + wbytes) {
    unsigned short* xb = (unsigned short*)d_ws;
    unsigned short* wb = (unsigned short*)((char*)d_ws + xbytes);
    l2b_conv_x<<<2048, 256, 0, stream>>>(x, xb, TOKENS * INF / 4);
    l2b_conv_w<<<2048, 256, 0, stream>>>(wq, wb, OUTF * INF / 4);
    l2b_gemm<<<dim3((TOKENS / 128) * (OUTF / 128)), 256, 0, stream>>>(
        xb, wb, scale, bias, out);
  } else {
    l2b_naive<<<(TOKENS * OUTF + 255) / 256, 256, 0, stream>>>(
        x, wq, scale, bias, out);
  }
}

// Round 9
// 297.024 us; speedup vs baseline: 1.1822x; 1.1822x over previous
//
#include <hip/hip_runtime.h>
#include <stdint.h>

#define TOKENS 8192
#define INF    4096
#define OUTF   4096
#define NT     64   // K-tiles of BK=64

typedef __bf16 bf16x8 __attribute__((ext_vector_type(8)));
typedef float  f32x4  __attribute__((ext_vector_type(4)));
typedef unsigned short ushort_t;

// ---------- fp32 -> bf16 (RNE) ----------
__device__ __forceinline__ unsigned short f2bf(float f) {
  union { float f; unsigned int u; } v;
  v.f = f;
  unsigned int r = v.u + 0x7fffu + ((v.u >> 16) & 1u);
  return (unsigned short)(r >> 16);
}

__global__ void l2b_conv_x(const float* __restrict__ x,
                           unsigned short* __restrict__ xb, int n4) {
  int idx = blockIdx.x * blockDim.x + threadIdx.x;
  int stride = gridDim.x * blockDim.x;
  for (int i = idx; i < n4; i += stride) {
    float4 v = reinterpret_cast<const float4*>(x)[i];
    ushort4 o;
    o.x = f2bf(v.x); o.y = f2bf(v.y); o.z = f2bf(v.z); o.w = f2bf(v.w);
    reinterpret_cast<ushort4*>(xb)[i] = o;
  }
}

__global__ void l2b_conv_w(const int* __restrict__ w,
                           unsigned short* __restrict__ wb, int n4) {
  int idx = blockIdx.x * blockDim.x + threadIdx.x;
  int stride = gridDim.x * blockDim.x;
  for (int i = idx; i < n4; i += stride) {
    int4 v = reinterpret_cast<const int4*>(w)[i];
    ushort4 o;  // {-2,-1,0,1}: exact in bf16
    o.x = f2bf((float)v.x); o.y = f2bf((float)v.y);
    o.z = f2bf((float)v.z); o.w = f2bf((float)v.w);
    reinterpret_cast<ushort4*>(wb)[i] = o;
  }
}

// ---------- async global->LDS, 16B/lane (dest = wave base + lane*16) ---------
__device__ __forceinline__ void gload_lds16(const ushort_t* g, ushort_t* l) {
  auto gp = reinterpret_cast<__attribute__((address_space(1))) unsigned int*>(
      reinterpret_cast<uintptr_t>(g));
  auto lp = reinterpret_cast<__attribute__((address_space(3))) unsigned int*>(
      reinterpret_cast<uintptr_t>(l));
  __builtin_amdgcn_global_load_lds(gp, lp, 16, 0, 0);
}

// ---------- st_16x32 swizzle on byte offsets within a 16 KiB half-slot -------
// (R3-proven: zero bank conflicts, refcheck-passed)
__device__ __forceinline__ int swz(int b) { return b ^ (((b >> 9) & 1) << 5); }

__device__ __forceinline__ bf16x8 ldsRd(const ushort_t* slot, int row, int colb) {
  int off = (row << 7) | colb;
  off ^= ((off >> 9) & 1) << 5;
  return *reinterpret_cast<const bf16x8*>(
      reinterpret_cast<const char*>(slot) + off);
}

// stage one 128x64 half-tile: 2 gloads/thread, linear LDS dest,
// inverse-swizzled per-lane global source (ge0/ge1 in elements)
__device__ __forceinline__ void stage_half(const ushort_t* __restrict__ src,
                                           ushort_t* slot, int wid,
                                           int ge0, int ge1) {
  gload_lds16(src + ge0, slot + wid * 512);
  gload_lds16(src + ge1, slot + 4096 + wid * 512);
}

__device__ __forceinline__ f32x4 mfma(bf16x8 a, bf16x8 b, f32x4 c) {
  return __builtin_amdgcn_mfma_f32_16x16x32_bf16(a, b, c, 0, 0, 0);
}

template <int N>
__device__ __forceinline__ void vmwait() {
  if constexpr (N == 4)      asm volatile("s_waitcnt vmcnt(4)" ::: "memory");
  else if constexpr (N == 0) asm volatile("s_waitcnt vmcnt(0)" ::: "memory");
}

// R3-proven phase sync (sched_barrier is load-bearing: R6 ablation -13%)
#define PHASE_SYNC()                                            \
  __builtin_amdgcn_s_barrier();                                 \
  asm volatile("s_waitcnt lgkmcnt(0)" ::: "memory");            \
  __builtin_amdgcn_sched_barrier(0);                            \
  __builtin_amdgcn_s_setprio(1)

// mid-phase sync: lgkm drain + pin, NO barrier (the R9 lever)
#define MID_SYNC()                                              \
  asm volatile("s_waitcnt lgkmcnt(0)" ::: "memory");            \
  __builtin_amdgcn_sched_barrier(0);                            \
  __builtin_amdgcn_s_setprio(1)

#define PHASE_END() __builtin_amdgcn_s_setprio(0)
#define BAR() __builtin_amdgcn_s_barrier()

// ---------------- one K-tile: 2 merged phases, 32 MFMA each ------------------
// Byte-identical reads/stages/vmcnt-ledger to R3; barriers 8 -> 3.
// PH_A: reads a0(m0-3, both kh: 8) + b0(4); stages A1(t+1), B0(t+1);
//       BAR+lgkm0 -> Q1 (a0 x b0, 16 MFMA); mid-read b1(4); lgkm0 -> Q2
//       (a0 x b1, 16); BAR.
// PH_B: reads a1(m4-7, both kh: 8); stages A0(t+2), B1(t+2);
//       BAR+lgkm0 -> Q3 (a1 x b1 regs, 16); mid-read b0(4); lgkm0 -> Q4
//       (a1 x b0, 16); vmcnt(4); BAR.
// Race ledger (as R3): every stage targets a slot whose readers drained at a
// wave-local lgkm(0) BEFORE a barrier that precedes the stage's issue; the
// tile-end vmcnt(4) forces the oldest 8 = all 4 half-tiles of t+1 before the
// tile-end barrier publishes them to all waves.
template <int VMB, bool STG1, bool STG2>
__device__ __forceinline__ void ktile(
    const ushort_t* __restrict__ A, const ushort_t* __restrict__ B,
    int rowBlk, int colBlk, int t,
    ushort_t* rA0, ushort_t* rA1, ushort_t* rB0, ushort_t* rB1,
    ushort_t* oA1, ushort_t* oB0,
    f32x4 (&acc)[8][4], int ar, int br, int fk, int wid, int ge0, int ge1) {
  bf16x8 a[4][2], b0[2][2], b1[2][2];
  // ================= merged phase A =================
#pragma unroll
  for (int m = 0; m < 4; ++m) {
    a[m][0] = ldsRd(rA0, ar + m * 16, fk * 16);
    a[m][1] = ldsRd(rA0, ar + m * 16, 64 + fk * 16);
  }
#pragma unroll
  for (int n = 0; n < 2; ++n) {
    b0[n][0] = ldsRd(rB0, br + n * 16, fk * 16);
    b0[n][1] = ldsRd(rB0, br + n * 16, 64 + fk * 16);
  }
  if (STG1) {
    stage_half(A + (size_t)(rowBlk + 128) * INF + (t + 1) * 64, oA1, wid, ge0, ge1);
    stage_half(B + (size_t)colBlk * INF + (t + 1) * 64, oB0, wid, ge0, ge1);
  }
  asm volatile("s_waitcnt lgkmcnt(8)" ::: "memory");  // early (12 reads)
  PHASE_SYNC();
#pragma unroll
  for (int m = 0; m < 4; ++m)
#pragma unroll
    for (int n = 0; n < 2; ++n) {
      acc[m][n] = mfma(a[m][0], b0[n][0], acc[m][n]);
      acc[m][n] = mfma(a[m][1], b0[n][1], acc[m][n]);
    }
  PHASE_END();
  // mid-phase: b1 reads overlap nothing-but-this-wave; no barrier
#pragma unroll
  for (int n = 0; n < 2; ++n) {
    b1[n][0] = ldsRd(rB1, br + n * 16, fk * 16);
    b1[n][1] = ldsRd(rB1, br + n * 16, 64 + fk * 16);
  }
  MID_SYNC();
#pragma unroll
  for (int m = 0; m < 4; ++m)
#pragma unroll
    for (int n = 0; n < 2; ++n) {
      acc[m][2 + n] = mfma(a[m][0], b1[n][0], acc[m][2 + n]);
      acc[m][2 + n] = mfma(a[m][1], b1[n][1], acc[m][2 + n]);
    }
  PHASE_END();
  BAR();
  // ================= merged phase B =================
#pragma unroll
  for (int m = 0; m < 4; ++m) {
    a[m][0] = ldsRd(rA1, ar + m * 16, fk * 16);
    a[m][1] = ldsRd(rA1, ar + m * 16, 64 + fk * 16);
  }
  if (STG2) {
    stage_half(A + (size_t)rowBlk * INF + (t + 2) * 64, rA0, wid, ge0, ge1);
    stage_half(B + (size_t)(colBlk + 128) * INF + (t + 2) * 64, rB1, wid, ge0, ge1);
  }
  PHASE_SYNC();
#pragma unroll
  for (int m = 0; m < 4; ++m)
#pragma unroll
    for (int n = 0; n < 2; ++n) {
      acc[4 + m][2 + n] = mfma(a[m][0], b1[n][0], acc[4 + m][2 + n]);
      acc[4 + m][2 + n] = mfma(a[m][1], b1[n][1], acc[4 + m][2 + n]);
    }
  PHASE_END();
  // mid-phase: re-read b0 (b0 regs were dead through Q2/Q3)
#pragma unroll
  for (int n = 0; n < 2; ++n) {
    b0[n][0] = ldsRd(rB0, br + n * 16, fk * 16);
    b0[n][1] = ldsRd(rB0, br + n * 16, 64 + fk * 16);
  }
  MID_SYNC();
#pragma unroll
  for (int m = 0; m < 4; ++m)
#pragma unroll
    for (int n = 0; n < 2; ++n) {
      acc[4 + m][n] = mfma(a[m][0], b0[n][0], acc[4 + m][n]);
      acc[4 + m][n] = mfma(a[m][1], b0[n][1], acc[4 + m][n]);
    }
  PHASE_END();
  if (VMB >= 0) vmwait<VMB >= 0 ? VMB : 0>();
  BAR();
}

// ---------------- 256x256 GEMM: C[t][o] = A[t][:] . B[o][:] ------------------
__global__ __launch_bounds__(512, 2) void l2b_gemm8(
    const ushort_t* __restrict__ A, const ushort_t* __restrict__ B,
    const float* __restrict__ scale, const float* __restrict__ bias,
    float* __restrict__ C) {
  extern __shared__ ushort_t smem[];  // 128 KiB = 8 half-slots of 16 KiB
  ushort_t* sA00 = smem;              ushort_t* sA01 = smem + 8192;
  ushort_t* sA10 = smem + 16384;      ushort_t* sA11 = smem + 24576;
  ushort_t* sB00 = smem + 32768;      ushort_t* sB01 = smem + 40960;
  ushort_t* sB10 = smem + 49152;      ushort_t* sB11 = smem + 57344;

  const int tid  = threadIdx.x;
  const int lane = tid & 63;
  const int wid  = tid >> 6;              // 0..7
  const int wm = wid >> 2, wn = wid & 3;  // 2x4 wave grid
  const int fr = lane & 15, fk = lane >> 4;
  const int ar = wm * 64 + fr;            // a-frag row within half
  const int br = wn * 32 + fr;            // b-frag row within half

  // XCD-aware swizzle (nwg=512, divisible by 8)
  const int bid = (int)blockIdx.x;
  const int idx = (bid & 7) * 64 + (bid >> 3);
  const int bm = idx >> 4, bn = idx & 15;
  const int rowBlk = bm * 256, colBlk = bn * 256;

  // inverse-swizzled per-lane global element offsets for the 2 staging rounds
  const int ob0 = wid * 1024 + lane * 16;       // byte off in half-slot, round 0
  const int ob1 = 8192 + ob0;                   // round 1
  const int p0 = swz(ob0), p1 = swz(ob1);
  const int ge0 = (p0 >> 7) * INF + ((p0 & 127) >> 1);
  const int ge1 = (p1 >> 7) * INF + ((p1 & 127) >> 1);

  // ---- prologue: steady-state stream order A0(0),B1(0),A1(0),B0(0),A0(1),B1(1)
  stage_half(A + (size_t)rowBlk * INF,               sA00, wid, ge0, ge1);
  stage_half(B + (size_t)(colBlk + 128) * INF,       sB01, wid, ge0, ge1);
  stage_half(A + (size_t)(rowBlk + 128) * INF,       sA01, wid, ge0, ge1);
  stage_half(B + (size_t)colBlk * INF,               sB00, wid, ge0, ge1);
  stage_half(A + (size_t)rowBlk * INF + 64,          sA10, wid, ge0, ge1);
  stage_half(B + (size_t)(colBlk + 128) * INF + 64,  sB11, wid, ge0, ge1);
  asm volatile("s_waitcnt vmcnt(4)" ::: "memory");   // tile 0 landed
  __builtin_amdgcn_s_barrier();

  f32x4 acc[8][4] = {};

#pragma unroll 1
  for (int i = 0; i < 31; ++i) {                     // tiles 0..61
    const int t = 2 * i;
    ktile<4, true, true>(A, B, rowBlk, colBlk, t,
        sA00, sA01, sB00, sB01, sA11, sB10,
        acc, ar, br, fk, wid, ge0, ge1);
    ktile<4, true, true>(A, B, rowBlk, colBlk, t + 1,
        sA10, sA11, sB10, sB11, sA01, sB00,
        acc, ar, br, fk, wid, ge0, ge1);
  }
  // tile 62 (parity 0): stage only t+1=63; drain vmcnt to 0 at boundary
  ktile<0, true, false>(A, B, rowBlk, colBlk, 62,
      sA00, sA01, sB00, sB01, sA11, sB10,
      acc, ar, br, fk, wid, ge0, ge1);
  // tile 63 (parity 1): compute only
  ktile<-1, false, false>(A, B, rowBlk, colBlk, 63,
      sA10, sA11, sB10, sB11, sA01, sB00,
      acc, ar, br, fk, wid, ge0, ge1);

  // ---- epilogue: y = acc*scale + bias; C/D: col=lane&15, row=(lane>>4)*4+j
  const float s = scale[0];
#pragma unroll
  for (int ni = 0; ni < 4; ++ni) {
    const int nh = ni >> 1, n = ni & 1;
    const int col = colBlk + nh * 128 + wn * 32 + n * 16 + fr;
    const float bv = bias[col];
#pragma unroll
    for (int mi = 0; mi < 8; ++mi) {
      const int mh = mi >> 2, m = mi & 3;
      const int row = rowBlk + mh * 128 + wm * 64 + m * 16 + fk * 4;
#pragma unroll
      for (int j = 0; j < 4; ++j)
        C[(size_t)(row + j) * OUTF + col] = acc[mi][ni][j] * s + bv;
    }
  }
}

// ---------------- fallback: R1 128x128 m97-structure GEMM -------------------
__global__ __launch_bounds__(256) void l2b_gemm(
    const ushort_t* __restrict__ A, const ushort_t* __restrict__ B,
    const float* __restrict__ scale, const float* __restrict__ bias,
    float* __restrict__ C) {
  constexpr int K = INF;
  constexpr int N = OUTF;
  __shared__ __align__(16) ushort_t ldsA[128 * 32];
  __shared__ __align__(16) ushort_t ldsB[128 * 32];
  const int tid = threadIdx.x;
  const int lane = tid & 63;
  const int wid = tid >> 6;
  const int wm = wid >> 1, wn = wid & 1;
  const int bm = blockIdx.x >> 5, bn = blockIdx.x & 31;
  const int row0 = bm * 128, col0 = bn * 128;
  const int lr = lane >> 4, lc = lane & 15;
  f32x4 acc[4][4] = {};
  for (int k0 = 0; k0 < K; k0 += 32) {
#pragma unroll
    for (int i = 0; i < 2; ++i) {
      const int idx = i * 256 + tid;
      const int r = idx >> 2;
      const int c = (idx & 3) * 8;
      ushort_t* lbaseA = ldsA + i * 2048 + wid * 512;
      ushort_t* lbaseB = ldsB + i * 2048 + wid * 512;
      gload_lds16(A + (size_t)(row0 + r) * K + (k0 + c), lbaseA);
      gload_lds16(B + (size_t)(col0 + r) * K + (k0 + c), lbaseB);
    }
    __syncthreads();
    bf16x8 af[4], bfr[4];
#pragma unroll
    for (int m = 0; m < 4; ++m)
      af[m] = *reinterpret_cast<const bf16x8*>(
          &ldsA[(wm * 64 + m * 16 + lc) * 32 + lr * 8]);
#pragma unroll
    for (int n = 0; n < 4; ++n)
      bfr[n] = *reinterpret_cast<const bf16x8*>(
          &ldsB[(wn * 64 + n * 16 + lc) * 32 + lr * 8]);
#pragma unroll
    for (int m = 0; m < 4; ++m)
#pragma unroll
      for (int n = 0; n < 4; ++n)
        acc[m][n] = mfma(af[m], bfr[n], acc[m][n]);
    __syncthreads();
  }
  const float s = scale[0];
#pragma unroll
  for (int n = 0; n < 4; ++n) {
    const int col = col0 + wn * 64 + n * 16 + lc;
    const float bv = bias[col];
#pragma unroll
    for (int m = 0; m < 4; ++m) {
      const int row = row0 + wm * 64 + m * 16 + lr * 4;
#pragma unroll
      for (int i = 0; i < 4; ++i)
        C[(size_t)(row + i) * N + col] = acc[m][n][i] * s + bv;
    }
  }
}

__global__ void l2b_naive(const float* __restrict__ x, const int* __restrict__ w,
                          const float* __restrict__ scale,
                          const float* __restrict__ bias,
                          float* __restrict__ out) {
  const int o = blockIdx.x * blockDim.x + threadIdx.x;
  if (o >= TOKENS * OUTF) return;
  const int t = o / OUTF;
  const int n = o - t * OUTF;
  const float* xr = x + (size_t)t * INF;
  const int* wr = w + (size_t)n * INF;
  float acc = 0.f;
  for (int k = 0; k < INF; ++k) acc += xr[k] * (float)wr[k];
  out[o] = acc * scale[0] + bias[n];
}

extern "C" void kernel_launch(void* const* d_in, const int* in_sizes, int n_in,
                              void* d_out, int out_size, void* d_ws, size_t ws_size,
                              hipStream_t stream) {
  const float* x     = (const float*)d_in[0];
  const int*   wq    = (const int*)d_in[1];
  const float* scale = (const float*)d_in[2];
  const float* bias  = (const float*)d_in[3];
  float* out = (float*)d_out;

  const size_t xbytes = (size_t)TOKENS * INF * 2;
  const size_t wbytes = (size_t)OUTF * INF * 2;

  if (ws_size >= xbytes + wbytes) {
    unsigned short* xb = (unsigned short*)d_ws;
    unsigned short* wb = (unsigned short*)((char*)d_ws + xbytes);
    l2b_conv_x<<<2048, 256, 0, stream>>>(x, xb, TOKENS * INF / 4);
    l2b_conv_w<<<2048, 256, 0, stream>>>(wq, wb, OUTF * INF / 4);

    hipError_t e = hipFuncSetAttribute(
        reinterpret_cast<const void*>(l2b_gemm8),
        hipFuncAttributeMaxDynamicSharedMemorySize, 131072);
    if (e == hipSuccess) {
      l2b_gemm8<<<dim3((TOKENS / 256) * (OUTF / 256)), 512, 131072, stream>>>(
          xb, wb, scale, bias, out);
    } else {
      l2b_gemm<<<dim3((TOKENS / 128) * (OUTF / 128)), 256, 0, stream>>>(
          xb, wb, scale, bias, out);
    }
  } else {
    l2b_naive<<<(TOKENS * OUTF + 255) / 256, 256, 0, stream>>>(
        x, wq, scale, bias, out);
  }
}

// Round 10
// 295.122 us; speedup vs baseline: 1.1898x; 1.0064x over previous
//
#include <hip/hip_runtime.h>
#include <stdint.h>

#define TOKENS 8192
#define INF    4096
#define OUTF   4096
#define NT     64   // K-tiles of BK=64

typedef __bf16 bf16x8 __attribute__((ext_vector_type(8)));
typedef float  f32x4  __attribute__((ext_vector_type(4)));
typedef unsigned short ushort_t;

// ---------- fp32 -> bf16 (RNE) ----------
__device__ __forceinline__ unsigned short f2bf(float f) {
  union { float f; unsigned int u; } v;
  v.f = f;
  unsigned int r = v.u + 0x7fffu + ((v.u >> 16) & 1u);
  return (unsigned short)(r >> 16);
}

__global__ void l2b_conv_x(const float* __restrict__ x,
                           unsigned short* __restrict__ xb, int n4) {
  int idx = blockIdx.x * blockDim.x + threadIdx.x;
  int stride = gridDim.x * blockDim.x;
  for (int i = idx; i < n4; i += stride) {
    float4 v = reinterpret_cast<const float4*>(x)[i];
    ushort4 o;
    o.x = f2bf(v.x); o.y = f2bf(v.y); o.z = f2bf(v.z); o.w = f2bf(v.w);
    reinterpret_cast<ushort4*>(xb)[i] = o;
  }
}

__global__ void l2b_conv_w(const int* __restrict__ w,
                           unsigned short* __restrict__ wb, int n4) {
  int idx = blockIdx.x * blockDim.x + threadIdx.x;
  int stride = gridDim.x * blockDim.x;
  for (int i = idx; i < n4; i += stride) {
    int4 v = reinterpret_cast<const int4*>(w)[i];
    ushort4 o;  // {-2,-1,0,1}: exact in bf16
    o.x = f2bf((float)v.x); o.y = f2bf((float)v.y);
    o.z = f2bf((float)v.z); o.w = f2bf((float)v.w);
    reinterpret_cast<ushort4*>(wb)[i] = o;
  }
}

// ---------- async global->LDS, 16B/lane (dest = wave base + lane*16) ---------
__device__ __forceinline__ void gload_lds16(const ushort_t* g, ushort_t* l) {
  auto gp = reinterpret_cast<__attribute__((address_space(1))) unsigned int*>(
      reinterpret_cast<uintptr_t>(g));
  auto lp = reinterpret_cast<__attribute__((address_space(3))) unsigned int*>(
      reinterpret_cast<uintptr_t>(l));
  __builtin_amdgcn_global_load_lds(gp, lp, 16, 0, 0);
}

// ---------- st_16x32 swizzle on byte offsets within a 16 KiB half-slot -------
__device__ __forceinline__ int swz(int b) { return b ^ (((b >> 9) & 1) << 5); }

// swizzled ds_read of one bf16x8 fragment from a [128][64] half-slot
__device__ __forceinline__ bf16x8 ldsRd(const ushort_t* slot, int row, int colb) {
  int off = (row << 7) | colb;
  off ^= ((off >> 9) & 1) << 5;
  return *reinterpret_cast<const bf16x8*>(
      reinterpret_cast<const char*>(slot) + off);
}

// stage one 128x64 half-tile: 2 gloads/thread, linear LDS dest,
// inverse-swizzled per-lane global source (ge0/ge1 in elements)
__device__ __forceinline__ void stage_half(const ushort_t* __restrict__ src,
                                           ushort_t* slot, int wid,
                                           int ge0, int ge1) {
  gload_lds16(src + ge0, slot + wid * 512);
  gload_lds16(src + ge1, slot + 4096 + wid * 512);
}

__device__ __forceinline__ f32x4 mfma(bf16x8 a, bf16x8 b, f32x4 c) {
  return __builtin_amdgcn_mfma_f32_16x16x32_bf16(a, b, c, 0, 0, 0);
}

template <int N>
__device__ __forceinline__ void vmwait() {
  if constexpr (N == 4)      asm volatile("s_waitcnt vmcnt(4)" ::: "memory");
  else if constexpr (N == 0) asm volatile("s_waitcnt vmcnt(0)" ::: "memory");
}

#define PHASE_SYNC()                                            \
  __builtin_amdgcn_s_barrier();                                 \
  asm volatile("s_waitcnt lgkmcnt(0)" ::: "memory");            \
  __builtin_amdgcn_sched_barrier(0);                            \
  __builtin_amdgcn_s_setprio(1)

#define PHASE_END() __builtin_amdgcn_s_setprio(0)

// ---------------- one K-tile: 4 phases, 16 MFMA each -------------------------
// reads: ph1 (A0,B0) -> acc[0..3][0..1]; ph2 (A0,B1) -> acc[0..3][2..3];
//        ph3 (A1,B1) -> acc[4..7][2..3]; ph4 (A1,B0) -> acc[4..7][0..1]
// stages: ph1 A1(t+1)->oA1; ph2 B0(t+1)->oB0; ph3 A0(t+2)->rA0; ph4 B1(t+2)->rB1
template <int VMB, bool STG1, bool STG2>
__device__ __forceinline__ void ktile(
    const ushort_t* __restrict__ A, const ushort_t* __restrict__ B,
    int rowBlk, int colBlk, int t,
    ushort_t* rA0, ushort_t* rA1, ushort_t* rB0, ushort_t* rB1,
    ushort_t* oA1, ushort_t* oB0,
    f32x4 (&acc)[8][4], int ar, int br, int fk, int wid, int ge0, int ge1) {
  bf16x8 a[4][2], b[2][2];
  // ---- phase 1 ----
#pragma unroll
  for (int m = 0; m < 4; ++m) {
    a[m][0] = ldsRd(rA0, ar + m * 16, fk * 16);
    a[m][1] = ldsRd(rA0, ar + m * 16, 64 + fk * 16);
  }
#pragma unroll
  for (int n = 0; n < 2; ++n) {
    b[n][0] = ldsRd(rB0, br + n * 16, fk * 16);
    b[n][1] = ldsRd(rB0, br + n * 16, 64 + fk * 16);
  }
  if (STG1)
    stage_half(A + (size_t)(rowBlk + 128) * INF + (t + 1) * 64, oA1, wid, ge0, ge1);
  PHASE_SYNC();
#pragma unroll
  for (int m = 0; m < 4; ++m)
#pragma unroll
    for (int n = 0; n < 2; ++n) {
      acc[m][n] = mfma(a[m][0], b[n][0], acc[m][n]);
      acc[m][n] = mfma(a[m][1], b[n][1], acc[m][n]);
    }
  PHASE_END();
  __builtin_amdgcn_s_barrier();
  // ---- phase 2 ----
#pragma unroll
  for (int n = 0; n < 2; ++n) {
    b[n][0] = ldsRd(rB1, br + n * 16, fk * 16);
    b[n][1] = ldsRd(rB1, br + n * 16, 64 + fk * 16);
  }
  if (STG1)
    stage_half(B + (size_t)colBlk * INF + (t + 1) * 64, oB0, wid, ge0, ge1);
  PHASE_SYNC();
#pragma unroll
  for (int m = 0; m < 4; ++m)
#pragma unroll
    for (int n = 0; n < 2; ++n) {
      acc[m][2 + n] = mfma(a[m][0], b[n][0], acc[m][2 + n]);
      acc[m][2 + n] = mfma(a[m][1], b[n][1], acc[m][2 + n]);
    }
  PHASE_END();
  __builtin_amdgcn_s_barrier();
  // ---- phase 3 (B1 frags reused from regs) ----
#pragma unroll
  for (int m = 0; m < 4; ++m) {
    a[m][0] = ldsRd(rA1, ar + m * 16, fk * 16);
    a[m][1] = ldsRd(rA1, ar + m * 16, 64 + fk * 16);
  }
  if (STG2)
    stage_half(A + (size_t)rowBlk * INF + (t + 2) * 64, rA0, wid, ge0, ge1);
  PHASE_SYNC();
#pragma unroll
  for (int m = 0; m < 4; ++m)
#pragma unroll
    for (int n = 0; n < 2; ++n) {
      acc[4 + m][2 + n] = mfma(a[m][0], b[n][0], acc[4 + m][2 + n]);
      acc[4 + m][2 + n] = mfma(a[m][1], b[n][1], acc[4 + m][2 + n]);
    }
  PHASE_END();
  __builtin_amdgcn_s_barrier();
  // ---- phase 4 (re-read B0) ----
#pragma unroll
  for (int n = 0; n < 2; ++n) {
    b[n][0] = ldsRd(rB0, br + n * 16, fk * 16);
    b[n][1] = ldsRd(rB0, br + n * 16, 64 + fk * 16);
  }
  if (STG2)
    stage_half(B + (size_t)(colBlk + 128) * INF + (t + 2) * 64, rB1, wid, ge0, ge1);
  PHASE_SYNC();
#pragma unroll
  for (int m = 0; m < 4; ++m)
#pragma unroll
    for (int n = 0; n < 2; ++n) {
      acc[4 + m][n] = mfma(a[m][0], b[n][0], acc[4 + m][n]);
      acc[4 + m][n] = mfma(a[m][1], b[n][1], acc[4 + m][n]);
    }
  PHASE_END();
  if (VMB >= 0) vmwait<VMB >= 0 ? VMB : 0>();
  __builtin_amdgcn_s_barrier();
}

// ---------------- 256x256 8-phase GEMM: C[t][o] = A[t][:] . B[o][:] ----------
__global__ __launch_bounds__(512, 2) void l2b_gemm8(
    const ushort_t* __restrict__ A, const ushort_t* __restrict__ B,
    const float* __restrict__ scale, const float* __restrict__ bias,
    float* __restrict__ C) {
  extern __shared__ ushort_t smem[];  // 128 KiB = 8 half-slots of 16 KiB
  ushort_t* sA00 = smem;              ushort_t* sA01 = smem + 8192;
  ushort_t* sA10 = smem + 16384;      ushort_t* sA11 = smem + 24576;
  ushort_t* sB00 = smem + 32768;      ushort_t* sB01 = smem + 40960;
  ushort_t* sB10 = smem + 49152;      ushort_t* sB11 = smem + 57344;

  const int tid  = threadIdx.x;
  const int lane = tid & 63;
  const int wid  = tid >> 6;              // 0..7
  const int wm = wid >> 2, wn = wid & 3;  // 2x4 wave grid
  const int fr = lane & 15, fk = lane >> 4;
  const int ar = wm * 64 + fr;            // a-frag row within half
  const int br = wn * 32 + fr;            // b-frag row within half

  // XCD-aware swizzle (nwg=512, divisible by 8)
  const int bid = (int)blockIdx.x;
  const int idx = (bid & 7) * 64 + (bid >> 3);
  const int bm = idx >> 4, bn = idx & 15;
  const int rowBlk = bm * 256, colBlk = bn * 256;

  // inverse-swizzled per-lane global element offsets for the 2 staging rounds
  const int ob0 = wid * 1024 + lane * 16;       // byte off in half-slot, round 0
  const int ob1 = 8192 + ob0;                   // round 1
  const int p0 = swz(ob0), p1 = swz(ob1);
  const int ge0 = (p0 >> 7) * INF + ((p0 & 127) >> 1);
  const int ge1 = (p1 >> 7) * INF + ((p1 & 127) >> 1);

  // ---- prologue: steady-state stream order A0(0),B1(0),A1(0),B0(0),A0(1),B1(1)
  stage_half(A + (size_t)rowBlk * INF,               sA00, wid, ge0, ge1);
  stage_half(B + (size_t)(colBlk + 128) * INF,       sB01, wid, ge0, ge1);
  stage_half(A + (size_t)(rowBlk + 128) * INF,       sA01, wid, ge0, ge1);
  stage_half(B + (size_t)colBlk * INF,               sB00, wid, ge0, ge1);
  stage_half(A + (size_t)rowBlk * INF + 64,          sA10, wid, ge0, ge1);
  stage_half(B + (size_t)(colBlk + 128) * INF + 64,  sB11, wid, ge0, ge1);
  asm volatile("s_waitcnt vmcnt(4)" ::: "memory");   // tile 0 landed
  __builtin_amdgcn_s_barrier();

  f32x4 acc[8][4] = {};

#pragma unroll 1
  for (int i = 0; i < 31; ++i) {                     // tiles 0..61
    const int t = 2 * i;
    ktile<4, true, true>(A, B, rowBlk, colBlk, t,
        sA00, sA01, sB00, sB01, sA11, sB10,
        acc, ar, br, fk, wid, ge0, ge1);
    ktile<4, true, true>(A, B, rowBlk, colBlk, t + 1,
        sA10, sA11, sB10, sB11, sA01, sB00,
        acc, ar, br, fk, wid, ge0, ge1);
  }
  // tile 62 (parity 0): stage only t+1=63; drain vmcnt to 0 at boundary
  ktile<0, true, false>(A, B, rowBlk, colBlk, 62,
      sA00, sA01, sB00, sB01, sA11, sB10,
      acc, ar, br, fk, wid, ge0, ge1);
  // tile 63 (parity 1): compute only
  ktile<-1, false, false>(A, B, rowBlk, colBlk, 63,
      sA10, sA11, sB10, sB11, sA01, sB00,
      acc, ar, br, fk, wid, ge0, ge1);

  // ---- epilogue: y = acc*scale + bias; C/D: col=lane&15, row=(lane>>4)*4+j
  const float s = scale[0];
#pragma unroll
  for (int ni = 0; ni < 4; ++ni) {
    const int nh = ni >> 1, n = ni & 1;
    const int col = colBlk + nh * 128 + wn * 32 + n * 16 + fr;
    const float bv = bias[col];
#pragma unroll
    for (int mi = 0; mi < 8; ++mi) {
      const int mh = mi >> 2, m = mi & 3;
      const int row = rowBlk + mh * 128 + wm * 64 + m * 16 + fk * 4;
#pragma unroll
      for (int j = 0; j < 4; ++j)
        C[(size_t)(row + j) * OUTF + col] = acc[mi][ni][j] * s + bv;
    }
  }
}

// ---------------- fallback: R1 128x128 m97-structure GEMM -------------------
__global__ __launch_bounds__(256) void l2b_gemm(
    const ushort_t* __restrict__ A, const ushort_t* __restrict__ B,
    const float* __restrict__ scale, const float* __restrict__ bias,
    float* __restrict__ C) {
  constexpr int K = INF;
  constexpr int N = OUTF;
  __shared__ __align__(16) ushort_t ldsA[128 * 32];
  __shared__ __align__(16) ushort_t ldsB[128 * 32];
  const int tid = threadIdx.x;
  const int lane = tid & 63;
  const int wid = tid >> 6;
  const int wm = wid >> 1, wn = wid & 1;
  const int bm = blockIdx.x >> 5, bn = blockIdx.x & 31;
  const int row0 = bm * 128, col0 = bn * 128;
  const int lr = lane >> 4, lc = lane & 15;
  f32x4 acc[4][4] = {};
  for (int k0 = 0; k0 < K; k0 += 32) {
#pragma unroll
    for (int i = 0; i < 2; ++i) {
      const int idx = i * 256 + tid;
      const int r = idx >> 2;
      const int c = (idx & 3) * 8;
      ushort_t* lbaseA = ldsA + i * 2048 + wid * 512;
      ushort_t* lbaseB = ldsB + i * 2048 + wid * 512;
      gload_lds16(A + (size_t)(row0 + r) * K + (k0 + c), lbaseA);
      gload_lds16(B + (size_t)(col0 + r) * K + (k0 + c), lbaseB);
    }
    __syncthreads();
    bf16x8 af[4], bfr[4];
#pragma unroll
    for (int m = 0; m < 4; ++m)
      af[m] = *reinterpret_cast<const bf16x8*>(
          &ldsA[(wm * 64 + m * 16 + lc) * 32 + lr * 8]);
#pragma unroll
    for (int n = 0; n < 4; ++n)
      bfr[n] = *reinterpret_cast<const bf16x8*>(
          &ldsB[(wn * 64 + n * 16 + lc) * 32 + lr * 8]);
#pragma unroll
    for (int m = 0; m < 4; ++m)
#pragma unroll
      for (int n = 0; n < 4; ++n)
        acc[m][n] = mfma(af[m], bfr[n], acc[m][n]);
    __syncthreads();
  }
  const float s = scale[0];
#pragma unroll
  for (int n = 0; n < 4; ++n) {
    const int col = col0 + wn * 64 + n * 16 + lc;
    const float bv = bias[col];
#pragma unroll
    for (int m = 0; m < 4; ++m) {
      const int row = row0 + wm * 64 + m * 16 + lr * 4;
#pragma unroll
      for (int i = 0; i < 4; ++i)
        C[(size_t)(row + i) * N + col] = acc[m][n][i] * s + bv;
    }
  }
}

__global__ void l2b_naive(const float* __restrict__ x, const int* __restrict__ w,
                          const float* __restrict__ scale,
                          const float* __restrict__ bias,
                          float* __restrict__ out) {
  const int o = blockIdx.x * blockDim.x + threadIdx.x;
  if (o >= TOKENS * OUTF) return;
  const int t = o / OUTF;
  const int n = o - t * OUTF;
  const float* xr = x + (size_t)t * INF;
  const int* wr = w + (size_t)n * INF;
  float acc = 0.f;
  for (int k = 0; k < INF; ++k) acc += xr[k] * (float)wr[k];
  out[o] = acc * scale[0] + bias[n];
}

extern "C" void kernel_launch(void* const* d_in, const int* in_sizes, int n_in,
                              void* d_out, int out_size, void* d_ws, size_t ws_size,
                              hipStream_t stream) {
  const float* x     = (const float*)d_in[0];
  const int*   wq    = (const int*)d_in[1];
  const float* scale = (const float*)d_in[2];
  const float* bias  = (const float*)d_in[3];
  float* out = (float*)d_out;

  const size_t xbytes = (size_t)TOKENS * INF * 2;
  const size_t wbytes = (size_t)OUTF * INF * 2;

  if (ws_size >= xbytes + wbytes) {
    unsigned short* xb = (unsigned short*)d_ws;
    unsigned short* wb = (unsigned short*)((char*)d_ws + xbytes);
    l2b_conv_x<<<2048, 256, 0, stream>>>(x, xb, TOKENS * INF / 4);
    l2b_conv_w<<<2048, 256, 0, stream>>>(wq, wb, OUTF * INF / 4);

    hipError_t e = hipFuncSetAttribute(
        reinterpret_cast<const void*>(l2b_gemm8),
        hipFuncAttributeMaxDynamicSharedMemorySize, 131072);
    if (e == hipSuccess) {
      l2b_gemm8<<<dim3((TOKENS / 256) * (OUTF / 256)), 512, 131072, stream>>>(
          xb, wb, scale, bias, out);
    } else {
      l2b_gemm<<<dim3((TOKENS / 128) * (OUTF / 128)), 256, 0, stream>>>(
          xb, wb, scale, bias, out);
    }
  } else {
    l2b_naive<<<(TOKENS * OUTF + 255) / 256, 256, 0, stream>>>(
        x, wq, scale, bias, out);
  }
}

// Round 11
// 263.282 us; speedup vs baseline: 1.3337x; 1.1209x over previous
//
#include <hip/hip_runtime.h>
#include <stdint.h>

#define TOKENS 8192
#define INF    4096
#define OUTF   4096
#define NT     64   // K-tiles of BK=64

typedef __bf16 bf16x8 __attribute__((ext_vector_type(8)));
typedef float  f32x4  __attribute__((ext_vector_type(4)));
typedef unsigned short ushort_t;

// ---------- fp32 -> bf16 (RNE) ----------
__device__ __forceinline__ unsigned short f2bf(float f) {
  union { float f; unsigned int u; } v;
  v.f = f;
  unsigned int r = v.u + 0x7fffu + ((v.u >> 16) & 1u);
  return (unsigned short)(r >> 16);
}

__global__ void l2b_conv_x(const float* __restrict__ x,
                           unsigned short* __restrict__ xb, int n4) {
  int idx = blockIdx.x * blockDim.x + threadIdx.x;
  int stride = gridDim.x * blockDim.x;
  for (int i = idx; i < n4; i += stride) {
    float4 v = reinterpret_cast<const float4*>(x)[i];
    ushort4 o;
    o.x = f2bf(v.x); o.y = f2bf(v.y); o.z = f2bf(v.z); o.w = f2bf(v.w);
    reinterpret_cast<ushort4*>(xb)[i] = o;
  }
}

__global__ void l2b_conv_w(const int* __restrict__ w,
                           unsigned short* __restrict__ wb, int n4) {
  int idx = blockIdx.x * blockDim.x + threadIdx.x;
  int stride = gridDim.x * blockDim.x;
  for (int i = idx; i < n4; i += stride) {
    int4 v = reinterpret_cast<const int4*>(w)[i];
    ushort4 o;  // {-2,-1,0,1}: exact in bf16
    o.x = f2bf((float)v.x); o.y = f2bf((float)v.y);
    o.z = f2bf((float)v.z); o.w = f2bf((float)v.w);
    reinterpret_cast<ushort4*>(wb)[i] = o;
  }
}

// ---------- async global->LDS, 16B/lane (dest = wave base + lane*16) ---------
__device__ __forceinline__ void gload_lds16(const ushort_t* g, ushort_t* l) {
  auto gp = reinterpret_cast<__attribute__((address_space(1))) unsigned int*>(
      reinterpret_cast<uintptr_t>(g));
  auto lp = reinterpret_cast<__attribute__((address_space(3))) unsigned int*>(
      reinterpret_cast<uintptr_t>(l));
  __builtin_amdgcn_global_load_lds(gp, lp, 16, 0, 0);
}

// ---------- full-bank swizzle: byte ^= (row&7)<<4 within [128][64] half-slot -
// Per ds_read_b128 (16 rows x 4 chunk-cols), position (kh*4+fk)^(r&7) covers
// all 8 x 16B positions 8x each -> 8 lanes/bank = 1KiB minimum, conflict-free
// by lane math (independent of compiler instruction selection).
__device__ __forceinline__ bf16x8 ldsRd(const ushort_t* slot, int row, int colb) {
  int off = ((row << 7) | colb) ^ ((row & 7) << 4);
  return *reinterpret_cast<const bf16x8*>(
      reinterpret_cast<const char*>(slot) + off);
}

// stage one 128x64 half-tile: 2 gloads/thread, linear LDS dest,
// inverse-swizzled per-lane global source (ge0/ge1 in elements)
__device__ __forceinline__ void stage_half(const ushort_t* __restrict__ src,
                                           ushort_t* slot, int wid,
                                           int ge0, int ge1) {
  gload_lds16(src + ge0, slot + wid * 512);
  gload_lds16(src + ge1, slot + 4096 + wid * 512);
}

__device__ __forceinline__ f32x4 mfma(bf16x8 a, bf16x8 b, f32x4 c) {
  return __builtin_amdgcn_mfma_f32_16x16x32_bf16(a, b, c, 0, 0, 0);
}

template <int N>
__device__ __forceinline__ void vmwait() {
  if constexpr (N == 4)      asm volatile("s_waitcnt vmcnt(4)" ::: "memory");
  else if constexpr (N == 0) asm volatile("s_waitcnt vmcnt(0)" ::: "memory");
}

#define PHASE_SYNC()                                            \
  __builtin_amdgcn_s_barrier();                                 \
  asm volatile("s_waitcnt lgkmcnt(0)" ::: "memory");            \
  __builtin_amdgcn_sched_barrier(0);                            \
  __builtin_amdgcn_s_setprio(1)

#define PHASE_END() __builtin_amdgcn_s_setprio(0)

// ---------------- one K-tile: 4 phases, 16 MFMA each -------------------------
// reads: ph1 (A0,B0) -> acc[0..3][0..1]; ph2 (A0,B1) -> acc[0..3][2..3];
//        ph3 (A1,B1) -> acc[4..7][2..3]; ph4 (A1,B0) -> acc[4..7][0..1]
// stages: ph1 A1(t+1)->oA1; ph2 B0(t+1)->oB0; ph3 A0(t+2)->rA0; ph4 B1(t+2)->rB1
// vmcnt(4) at tile end: 12 outstanding -> forces the 8 oldest = ALL of tile
// (t+1)'s halves; leaves A0(t+2),B1(t+2) in flight (R3-proven ledger).
template <int VMB, bool STG1, bool STG2>
__device__ __forceinline__ void ktile(
    const ushort_t* __restrict__ A, const ushort_t* __restrict__ B,
    int rowBlk, int colBlk, int t,
    ushort_t* rA0, ushort_t* rA1, ushort_t* rB0, ushort_t* rB1,
    ushort_t* oA1, ushort_t* oB0,
    f32x4 (&acc)[8][4], int ar, int br, int fk, int wid, int ge0, int ge1) {
  bf16x8 a[4][2], b[2][2];
  // ---- phase 1 ----
#pragma unroll
  for (int m = 0; m < 4; ++m) {
    a[m][0] = ldsRd(rA0, ar + m * 16, fk * 16);
    a[m][1] = ldsRd(rA0, ar + m * 16, 64 + fk * 16);
  }
#pragma unroll
  for (int n = 0; n < 2; ++n) {
    b[n][0] = ldsRd(rB0, br + n * 16, fk * 16);
    b[n][1] = ldsRd(rB0, br + n * 16, 64 + fk * 16);
  }
  if (STG1)
    stage_half(A + (size_t)(rowBlk + 128) * INF + (t + 1) * 64, oA1, wid, ge0, ge1);
  PHASE_SYNC();
#pragma unroll
  for (int m = 0; m < 4; ++m)
#pragma unroll
    for (int n = 0; n < 2; ++n) {
      acc[m][n] = mfma(a[m][0], b[n][0], acc[m][n]);
      acc[m][n] = mfma(a[m][1], b[n][1], acc[m][n]);
    }
  PHASE_END();
  __builtin_amdgcn_s_barrier();
  // ---- phase 2 ----
#pragma unroll
  for (int n = 0; n < 2; ++n) {
    b[n][0] = ldsRd(rB1, br + n * 16, fk * 16);
    b[n][1] = ldsRd(rB1, br + n * 16, 64 + fk * 16);
  }
  if (STG1)
    stage_half(B + (size_t)colBlk * INF + (t + 1) * 64, oB0, wid, ge0, ge1);
  PHASE_SYNC();
#pragma unroll
  for (int m = 0; m < 4; ++m)
#pragma unroll
    for (int n = 0; n < 2; ++n) {
      acc[m][2 + n] = mfma(a[m][0], b[n][0], acc[m][2 + n]);
      acc[m][2 + n] = mfma(a[m][1], b[n][1], acc[m][2 + n]);
    }
  PHASE_END();
  __builtin_amdgcn_s_barrier();
  // ---- phase 3 (B1 frags reused from regs) ----
#pragma unroll
  for (int m = 0; m < 4; ++m) {
    a[m][0] = ldsRd(rA1, ar + m * 16, fk * 16);
    a[m][1] = ldsRd(rA1, ar + m * 16, 64 + fk * 16);
  }
  if (STG2)
    stage_half(A + (size_t)rowBlk * INF + (t + 2) * 64, rA0, wid, ge0, ge1);
  PHASE_SYNC();
#pragma unroll
  for (int m = 0; m < 4; ++m)
#pragma unroll
    for (int n = 0; n < 2; ++n) {
      acc[4 + m][2 + n] = mfma(a[m][0], b[n][0], acc[4 + m][2 + n]);
      acc[4 + m][2 + n] = mfma(a[m][1], b[n][1], acc[4 + m][2 + n]);
    }
  PHASE_END();
  __builtin_amdgcn_s_barrier();
  // ---- phase 4 (re-read B0) ----
#pragma unroll
  for (int n = 0; n < 2; ++n) {
    b[n][0] = ldsRd(rB0, br + n * 16, fk * 16);
    b[n][1] = ldsRd(rB0, br + n * 16, 64 + fk * 16);
  }
  if (STG2)
    stage_half(B + (size_t)(colBlk + 128) * INF + (t + 2) * 64, rB1, wid, ge0, ge1);
  PHASE_SYNC();
#pragma unroll
  for (int m = 0; m < 4; ++m)
#pragma unroll
    for (int n = 0; n < 2; ++n) {
      acc[4 + m][n] = mfma(a[m][0], b[n][0], acc[4 + m][n]);
      acc[4 + m][n] = mfma(a[m][1], b[n][1], acc[4 + m][n]);
    }
  PHASE_END();
  if (VMB >= 0) vmwait<VMB >= 0 ? VMB : 0>();
  __builtin_amdgcn_s_barrier();
}

// ---------------- 256x256 8-phase GEMM: C[t][o] = A[t][:] . B[o][:] ----------
__global__ __launch_bounds__(512, 2) void l2b_gemm8(
    const ushort_t* __restrict__ A, const ushort_t* __restrict__ B,
    const float* __restrict__ scale, const float* __restrict__ bias,
    float* __restrict__ C) {
  extern __shared__ ushort_t smem[];  // 128 KiB = 8 half-slots of 16 KiB
  ushort_t* sA00 = smem;              ushort_t* sA01 = smem + 8192;
  ushort_t* sA10 = smem + 16384;      ushort_t* sA11 = smem + 24576;
  ushort_t* sB00 = smem + 32768;      ushort_t* sB01 = smem + 40960;
  ushort_t* sB10 = smem + 49152;      ushort_t* sB11 = smem + 57344;

  const int tid  = threadIdx.x;
  const int lane = tid & 63;
  const int wid  = tid >> 6;              // 0..7
  const int wm = wid >> 2, wn = wid & 3;  // 2x4 wave grid
  const int fr = lane & 15, fk = lane >> 4;
  const int ar = wm * 64 + fr;            // a-frag row within half
  const int br = wn * 32 + fr;            // b-frag row within half

  // XCD-aware swizzle (nwg=512, divisible by 8)
  const int bid = (int)blockIdx.x;
  const int idx = (bid & 7) * 64 + (bid >> 3);
  const int bm = idx >> 4, bn = idx & 15;
  const int rowBlk = bm * 256, colBlk = bn * 256;

  // inverse-swizzled per-lane global element offsets for the 2 staging rounds:
  // physical byte P (linear write) must hold logical byte P ^ ((row&7)<<4)
  const int ob0 = wid * 1024 + lane * 16;       // physical byte off, round 0
  const int ob1 = 8192 + ob0;                   // round 1
  const int r0 = ob0 >> 7, r1 = ob1 >> 7;
  const int c0 = (ob0 & 127) ^ ((r0 & 7) << 4);
  const int c1 = (ob1 & 127) ^ ((r1 & 7) << 4);
  const int ge0 = r0 * INF + (c0 >> 1);
  const int ge1 = r1 * INF + (c1 >> 1);

  // ---- prologue: steady-state stream order A0(0),B1(0),A1(0),B0(0),A0(1),B1(1)
  stage_half(A + (size_t)rowBlk * INF,               sA00, wid, ge0, ge1);
  stage_half(B + (size_t)(colBlk + 128) * INF,       sB01, wid, ge0, ge1);
  stage_half(A + (size_t)(rowBlk + 128) * INF,       sA01, wid, ge0, ge1);
  stage_half(B + (size_t)colBlk * INF,               sB00, wid, ge0, ge1);
  stage_half(A + (size_t)rowBlk * INF + 64,          sA10, wid, ge0, ge1);
  stage_half(B + (size_t)(colBlk + 128) * INF + 64,  sB11, wid, ge0, ge1);
  asm volatile("s_waitcnt vmcnt(4)" ::: "memory");   // tile 0 landed
  __builtin_amdgcn_s_barrier();

  f32x4 acc[8][4] = {};

#pragma unroll 1
  for (int i = 0; i < 31; ++i) {                     // tiles 0..61
    const int t = 2 * i;
    ktile<4, true, true>(A, B, rowBlk, colBlk, t,
        sA00, sA01, sB00, sB01, sA11, sB10,
        acc, ar, br, fk, wid, ge0, ge1);
    ktile<4, true, true>(A, B, rowBlk, colBlk, t + 1,
        sA10, sA11, sB10, sB11, sA01, sB00,
        acc, ar, br, fk, wid, ge0, ge1);
  }
  // tile 62 (parity 0): stage only t+1=63; drain vmcnt to 0 at boundary
  ktile<0, true, false>(A, B, rowBlk, colBlk, 62,
      sA00, sA01, sB00, sB01, sA11, sB10,
      acc, ar, br, fk, wid, ge0, ge1);
  // tile 63 (parity 1): compute only
  ktile<-1, false, false>(A, B, rowBlk, colBlk, 63,
      sA10, sA11, sB10, sB11, sA01, sB00,
      acc, ar, br, fk, wid, ge0, ge1);

  // ---- epilogue: y = acc*scale + bias; C/D: col=lane&15, row=(lane>>4)*4+j
  const float s = scale[0];
#pragma unroll
  for (int ni = 0; ni < 4; ++ni) {
    const int nh = ni >> 1, n = ni & 1;
    const int col = colBlk + nh * 128 + wn * 32 + n * 16 + fr;
    const float bv = bias[col];
#pragma unroll
    for (int mi = 0; mi < 8; ++mi) {
      const int mh = mi >> 2, m = mi & 3;
      const int row = rowBlk + mh * 128 + wm * 64 + m * 16 + fk * 4;
#pragma unroll
      for (int j = 0; j < 4; ++j)
        C[(size_t)(row + j) * OUTF + col] = acc[mi][ni][j] * s + bv;
    }
  }
}

// ---------------- fallback: R1 128x128 m97-structure GEMM -------------------
__global__ __launch_bounds__(256) void l2b_gemm(
    const ushort_t* __restrict__ A, const ushort_t* __restrict__ B,
    const float* __restrict__ scale, const float* __restrict__ bias,
    float* __restrict__ C) {
  constexpr int K = INF;
  constexpr int N = OUTF;
  __shared__ __align__(16) ushort_t ldsA[128 * 32];
  __shared__ __align__(16) ushort_t ldsB[128 * 32];
  const int tid = threadIdx.x;
  const int lane = tid & 63;
  const int wid = tid >> 6;
  const int wm = wid >> 1, wn = wid & 1;
  const int bm = blockIdx.x >> 5, bn = blockIdx.x & 31;
  const int row0 = bm * 128, col0 = bn * 128;
  const int lr = lane >> 4, lc = lane & 15;
  f32x4 acc[4][4] = {};
  for (int k0 = 0; k0 < K; k0 += 32) {
#pragma unroll
    for (int i = 0; i < 2; ++i) {
      const int idx = i * 256 + tid;
      const int r = idx >> 2;
      const int c = (idx & 3) * 8;
      ushort_t* lbaseA = ldsA + i * 2048 + wid * 512;
      ushort_t* lbaseB = ldsB + i * 2048 + wid * 512;
      gload_lds16(A + (size_t)(row0 + r) * K + (k0 + c), lbaseA);
      gload_lds16(B + (size_t)(col0 + r) * K + (k0 + c), lbaseB);
    }
    __syncthreads();
    bf16x8 af[4], bfr[4];
#pragma unroll
    for (int m = 0; m < 4; ++m)
      af[m] = *reinterpret_cast<const bf16x8*>(
          &ldsA[(wm * 64 + m * 16 + lc) * 32 + lr * 8]);
#pragma unroll
    for (int n = 0; n < 4; ++n)
      bfr[n] = *reinterpret_cast<const bf16x8*>(
          &ldsB[(wn * 64 + n * 16 + lc) * 32 + lr * 8]);
#pragma unroll
    for (int m = 0; m < 4; ++m)
#pragma unroll
      for (int n = 0; n < 4; ++n)
        acc[m][n] = mfma(af[m], bfr[n], acc[m][n]);
    __syncthreads();
  }
  const float s = scale[0];
#pragma unroll
  for (int n = 0; n < 4; ++n) {
    const int col = col0 + wn * 64 + n * 16 + lc;
    const float bv = bias[col];
#pragma unroll
    for (int m = 0; m < 4; ++m) {
      const int row = row0 + wm * 64 + m * 16 + lr * 4;
#pragma unroll
      for (int i = 0; i < 4; ++i)
        C[(size_t)(row + i) * N + col] = acc[m][n][i] * s + bv;
    }
  }
}

__global__ void l2b_naive(const float* __restrict__ x, const int* __restrict__ w,
                          const float* __restrict__ scale,
                          const float* __restrict__ bias,
                          float* __restrict__ out) {
  const int o = blockIdx.x * blockDim.x + threadIdx.x;
  if (o >= TOKENS * OUTF) return;
  const int t = o / OUTF;
  const int n = o - t * OUTF;
  const float* xr = x + (size_t)t * INF;
  const int* wr = w + (size_t)n * INF;
  float acc = 0.f;
  for (int k = 0; k < INF; ++k) acc += xr[k] * (float)wr[k];
  out[o] = acc * scale[0] + bias[n];
}

extern "C" void kernel_launch(void* const* d_in, const int* in_sizes, int n_in,
                              void* d_out, int out_size, void* d_ws, size_t ws_size,
                              hipStream_t stream) {
  const float* x     = (const float*)d_in[0];
  const int*   wq    = (const int*)d_in[1];
  const float* scale = (const float*)d_in[2];
  const float* bias  = (const float*)d_in[3];
  float* out = (float*)d_out;

  const size_t xbytes = (size_t)TOKENS * INF * 2;
  const size_t wbytes = (size_t)OUTF * INF * 2;

  if (ws_size >= xbytes + wbytes) {
    unsigned short* xb = (unsigned short*)d_ws;
    unsigned short* wb = (unsigned short*)((char*)d_ws + xbytes);
    l2b_conv_x<<<2048, 256, 0, stream>>>(x, xb, TOKENS * INF / 4);
    l2b_conv_w<<<2048, 256, 0, stream>>>(wq, wb, OUTF * INF / 4);

    hipError_t e = hipFuncSetAttribute(
        reinterpret_cast<const void*>(l2b_gemm8),
        hipFuncAttributeMaxDynamicSharedMemorySize, 131072);
    if (e == hipSuccess) {
      l2b_gemm8<<<dim3((TOKENS / 256) * (OUTF / 256)), 512, 131072, stream>>>(
          xb, wb, scale, bias, out);
    } else {
      l2b_gemm<<<dim3((TOKENS / 128) * (OUTF / 128)), 256, 0, stream>>>(
          xb, wb, scale, bias, out);
    }
  } else {
    l2b_naive<<<(TOKENS * OUTF + 255) / 256, 256, 0, stream>>>(
        x, wq, scale, bias, out);
  }
}